// Round 3
// baseline (262.619 us; speedup 1.0000x reference)
//
#include <hip/hip_runtime.h>

// MultiScaleRoIAlign via LDS patch staging.
// B=2, C=256, L=256 -> K=512 ROIs. out (K,256,7,7) fp32.
// Levels: (200,200,1/4) (100,100,1/8) (50,50,1/16) (25,25,1/32).
// SR=2 subsamples/bin-axis, bilinear, avg 4.
//
// Block = (256 thr) handles (roi k = blockIdx.y, 4 channels c0=blockIdx.x*4).
// Phase 1: stage the ROI's feature patch (dense rows, coalesced) for 4
//          channels into LDS + build 14-entry x/y tap tables.
// Phase 2: 196 threads compute 4x49 outputs from LDS.
// Rationale: tap addresses are identical across channels; patch <= ~930 px
// (bounded by level assignment: a=w*scale<=128, a*b<784 at lvl2; +borders).

#define OUT_HW 7
#define NCH 256
#define CC 4            // channels staged per block
#define PATCH_MAX 1024  // floats per channel plane (worst case ~930)

__global__ __launch_bounds__(256) void msroi_lds_kernel(
    const float* __restrict__ f0, const float* __restrict__ f1,
    const float* __restrict__ f2, const float* __restrict__ f3,
    const float* __restrict__ boxes, float* __restrict__ out)
{
    const int tid = threadIdx.x;
    const int k  = blockIdx.y;          // roi index 0..511
    const int c0 = blockIdx.x * CC;     // first channel of this block
    const int b  = k >> 8;              // batch = k/256

    __shared__ float s_patch[CC * PATCH_MAX];
    __shared__ int   s_xlo[14], s_xhi[14], s_ylo[14], s_yhi[14];
    __shared__ float s_lx[14], s_ly[14];

    // ---- per-ROI setup (uniform across block; computed redundantly) ----
    const float bx1 = boxes[k * 4 + 0];
    const float by1 = boxes[k * 4 + 1];
    const float bx2 = boxes[k * 4 + 2];
    const float by2 = boxes[k * 4 + 3];

    const float area = (bx2 - bx1) * (by2 - by1);
    const float s = sqrtf(area);
    float lvlf = floorf(4.0f + log2f(s * (1.0f / 224.0f)) + 1e-6f);
    lvlf = fminf(fmaxf(lvlf, 2.0f), 5.0f);
    const int lvl = (int)lvlf - 2;

    const float* feat;
    int H, W;
    float scale;
    if (lvl == 0)      { feat = f0; H = 200; W = 200; scale = 0.25f;    }
    else if (lvl == 1) { feat = f1; H = 100; W = 100; scale = 0.125f;   }
    else if (lvl == 2) { feat = f2; H = 50;  W = 50;  scale = 0.0625f;  }
    else               { feat = f3; H = 25;  W = 25;  scale = 0.03125f; }

    const float x1 = bx1 * scale;
    const float y1 = by1 * scale;
    const float roi_w = fmaxf(bx2 * scale - x1, 1.0f);
    const float roi_h = fmaxf(by2 * scale - y1, 1.0f);
    const float bin_w = roi_w * (1.0f / OUT_HW);
    const float bin_h = roi_h * (1.0f / OUT_HW);

    // patch bounds from extreme samples (x monotone over sample index i=0..13:
    // x = x1 + (0.5*i + 0.25) * bin_w)
    // _prep_coords semantics: cm=max(c,0); lo=trunc(cm); at_edge: lo=hi=size-1.
    auto prep_lo = [](float c, int size) {
        float cm = fmaxf(c, 0.0f);
        int lo = (int)cm;
        return (lo >= size - 1) ? (size - 1) : lo;
    };
    auto prep_hi = [](float c, int size) {
        float cm = fmaxf(c, 0.0f);
        int lo = (int)cm;
        return (lo >= size - 1) ? (size - 1) : (lo + 1);
    };
    const int px0 = prep_lo(x1 + 0.25f * bin_w, W);
    const int px1 = prep_hi(x1 + 6.75f * bin_w, W);
    const int py0 = prep_lo(y1 + 0.25f * bin_h, H);
    const int py1 = prep_hi(y1 + 6.75f * bin_h, H);
    const int pw_cnt = px1 - px0 + 1;
    const int ph_cnt = py1 - py0 + 1;

    // ---- tap tables (threads 0..13: x, 32..45: y) ----
    if (tid < 14) {
        float x = x1 + ((float)tid * 0.5f + 0.25f) * bin_w;
        float cm = fmaxf(x, 0.0f);
        int lo = (int)cm;
        int hi;
        if (lo >= W - 1) { lo = W - 1; hi = W - 1; }
        else             { hi = lo + 1; }
        s_xlo[tid] = lo - px0;
        s_xhi[tid] = hi - px0;
        s_lx[tid]  = cm - (float)lo;
    } else if (tid >= 32 && tid < 46) {
        int i = tid - 32;
        float y = y1 + ((float)i * 0.5f + 0.25f) * bin_h;
        float cm = fmaxf(y, 0.0f);
        int lo = (int)cm;
        int hi;
        if (lo >= H - 1) { lo = H - 1; hi = H - 1; }
        else             { hi = lo + 1; }
        s_ylo[i] = lo - py0;
        s_yhi[i] = hi - py0;
        s_ly[i]  = cm - (float)lo;
    }

    // ---- phase 1: stage patches, dense coalesced rows ----
    const int tx = tid & 31;       // column lane
    const int ty = tid >> 5;       // row-group 0..7
    const size_t HW = (size_t)H * W;
    const size_t bc = (size_t)b * NCH + c0;
    const int rows_total = CC * ph_cnt;

    for (int rr = ty; rr < rows_total; rr += 8) {
        int cl = (rr >= ph_cnt) + (rr >= 2 * ph_cnt) + (rr >= 3 * ph_cnt);
        int r = rr - cl * ph_cnt;
        const float* src = feat + (bc + cl) * HW + (size_t)(py0 + r) * W + px0;
        float* dst = &s_patch[cl * PATCH_MAX + r * pw_cnt];
        for (int col = tx; col < pw_cnt; col += 32)
            dst[col] = src[col];
    }
    __syncthreads();

    // ---- phase 2: compute 4x49 outputs from LDS ----
    if (tid < CC * 49) {
        const int cl  = tid / 49;
        const int pix = tid % 49;
        const int ph  = pix / 7;
        const int pw  = pix % 7;

        float acc = 0.0f;
        const float* patch = &s_patch[cl * PATCH_MAX];
#pragma unroll
        for (int iy = 0; iy < 2; ++iy) {
            const int sy = ph * 2 + iy;
            const int r0 = s_ylo[sy] * pw_cnt;
            const int r1 = s_yhi[sy] * pw_cnt;
            const float ly = s_ly[sy];
            const float hy = 1.0f - ly;
#pragma unroll
            for (int ix = 0; ix < 2; ++ix) {
                const int sx = pw * 2 + ix;
                const int xlo = s_xlo[sx];
                const int xhi = s_xhi[sx];
                const float lx = s_lx[sx];
                const float hx = 1.0f - lx;
                const float v00 = patch[r0 + xlo];
                const float v01 = patch[r0 + xhi];
                const float v10 = patch[r1 + xlo];
                const float v11 = patch[r1 + xhi];
                acc += hy * hx * v00 + hy * lx * v01 + ly * hx * v10 + ly * lx * v11;
            }
        }
        // output: 196 consecutive floats per block
        out[((size_t)k * NCH + c0) * 49 + tid] = acc * 0.25f;
    }
}

extern "C" void kernel_launch(void* const* d_in, const int* in_sizes, int n_in,
                              void* d_out, int out_size, void* d_ws, size_t ws_size,
                              hipStream_t stream)
{
    const float* f0 = (const float*)d_in[0];
    const float* f1 = (const float*)d_in[1];
    const float* f2 = (const float*)d_in[2];
    const float* f3 = (const float*)d_in[3];
    const float* boxes = (const float*)d_in[4];
    float* out = (float*)d_out;

    dim3 grid(NCH / CC, 512, 1);   // (64 channel-blocks, 512 rois)
    dim3 block(256, 1, 1);
    msroi_lds_kernel<<<grid, block, 0, stream>>>(f0, f1, f2, f3, boxes, out);
}

// Round 4
// 179.878 us; speedup vs baseline: 1.4600x; 1.4600x over previous
//
#include <hip/hip_runtime.h>

// MultiScaleRoIAlign via LDS patch staging, flat-mapped staging loop.
// B=2, C=256, L=256 -> K=512 ROIs. out (K,256,7,7) fp32.
// Levels: (200,200,1/4) (100,100,1/8) (50,50,1/16) (25,25,1/32).
// SR=2 subsamples/bin-axis, bilinear, avg 4.
//
// Block (256 thr) = (roi k = blockIdx.y, 4 channels c0 = blockIdx.x*4).
// Phase 1: stage ROI patch for 4 channels into LDS; thread i loads flat patch
//          pixel i for all 4 channels (all lanes active, coalesced rows).
// Phase 2: 196 threads compute 4x49 outputs from LDS.
// Patch bound: w'h' < 784 at any level, span 0.9286*roi' + 2 -> patch <= 930.

#define OUT_HW 7
#define NCH 256
#define CC 4
#define PATCH_MAX 960   // floats per channel plane (worst case ~930)

__global__ __launch_bounds__(256) void msroi_lds2_kernel(
    const float* __restrict__ f0, const float* __restrict__ f1,
    const float* __restrict__ f2, const float* __restrict__ f3,
    const float* __restrict__ boxes, float* __restrict__ out)
{
    const int tid = threadIdx.x;
    const int k  = blockIdx.y;          // roi 0..511
    const int c0 = blockIdx.x * CC;     // first channel
    const int b  = k >> 8;              // batch

    __shared__ float s_patch[CC * PATCH_MAX];
    __shared__ int   s_xlo[14], s_xhi[14], s_ylo[14], s_yhi[14];
    __shared__ float s_lx[14], s_ly[14];

    // ---- per-ROI setup (uniform; SIMT-redundant is fine) ----
    const float bx1 = boxes[k * 4 + 0];
    const float by1 = boxes[k * 4 + 1];
    const float bx2 = boxes[k * 4 + 2];
    const float by2 = boxes[k * 4 + 3];

    const float area = (bx2 - bx1) * (by2 - by1);
    const float s = sqrtf(area);
    float lvlf = floorf(4.0f + log2f(s * (1.0f / 224.0f)) + 1e-6f);
    lvlf = fminf(fmaxf(lvlf, 2.0f), 5.0f);
    const int lvl = (int)lvlf - 2;

    const float* feat;
    int H, W;
    float scale;
    if (lvl == 0)      { feat = f0; H = 200; W = 200; scale = 0.25f;    }
    else if (lvl == 1) { feat = f1; H = 100; W = 100; scale = 0.125f;   }
    else if (lvl == 2) { feat = f2; H = 50;  W = 50;  scale = 0.0625f;  }
    else               { feat = f3; H = 25;  W = 25;  scale = 0.03125f; }

    const float x1 = bx1 * scale;
    const float y1 = by1 * scale;
    const float roi_w = fmaxf(bx2 * scale - x1, 1.0f);
    const float roi_h = fmaxf(by2 * scale - y1, 1.0f);
    const float bin_w = roi_w * (1.0f / OUT_HW);
    const float bin_h = roi_h * (1.0f / OUT_HW);

    // patch bounds from extreme samples (monotone in sample index)
    auto prep_lo = [](float c, int size) {
        float cm = fmaxf(c, 0.0f);
        int lo = (int)cm;
        return (lo >= size - 1) ? (size - 1) : lo;
    };
    auto prep_hi = [](float c, int size) {
        float cm = fmaxf(c, 0.0f);
        int lo = (int)cm;
        return (lo >= size - 1) ? (size - 1) : (lo + 1);
    };
    const int px0 = prep_lo(x1 + 0.25f * bin_w, W);
    const int px1 = prep_hi(x1 + 6.75f * bin_w, W);
    const int py0 = prep_lo(y1 + 0.25f * bin_h, H);
    const int py1 = prep_hi(y1 + 6.75f * bin_h, H);
    const int pw_cnt = px1 - px0 + 1;
    const int ph_cnt = py1 - py0 + 1;
    const int patch_px = pw_cnt * ph_cnt;

    // ---- tap tables (threads 0..13: x, 32..45: y) ----
    if (tid < 14) {
        float x = x1 + ((float)tid * 0.5f + 0.25f) * bin_w;
        float cm = fmaxf(x, 0.0f);
        int lo = (int)cm;
        int hi;
        if (lo >= W - 1) { lo = W - 1; hi = W - 1; }
        else             { hi = lo + 1; }
        s_xlo[tid] = lo - px0;
        s_xhi[tid] = hi - px0;
        s_lx[tid]  = cm - (float)lo;
    } else if (tid >= 32 && tid < 46) {
        int i = tid - 32;
        float y = y1 + ((float)i * 0.5f + 0.25f) * bin_h;
        float cm = fmaxf(y, 0.0f);
        int lo = (int)cm;
        int hi;
        if (lo >= H - 1) { lo = H - 1; hi = H - 1; }
        else             { hi = lo + 1; }
        s_ylo[i] = lo - py0;
        s_yhi[i] = hi - py0;
        s_ly[i]  = cm - (float)lo;
    }

    // ---- phase 1: flat-mapped staging, all lanes active ----
    const size_t HW = (size_t)H * W;
    const float* base = feat + ((size_t)b * NCH + c0) * HW;
    const float inv_pw = 1.0f / (float)pw_cnt;

    for (int i = tid; i < patch_px; i += 256) {
        int r = (int)((float)i * inv_pw);
        int col = i - r * pw_cnt;
        if (col < 0)        { col += pw_cnt; --r; }
        if (col >= pw_cnt)  { col -= pw_cnt; ++r; }
        const float* src = base + (size_t)(py0 + r) * W + (px0 + col);
        s_patch[0 * PATCH_MAX + i] = src[0];
        s_patch[1 * PATCH_MAX + i] = src[HW];
        s_patch[2 * PATCH_MAX + i] = src[2 * HW];
        s_patch[3 * PATCH_MAX + i] = src[3 * HW];
    }
    __syncthreads();

    // ---- phase 2: 196 threads compute 4x49 outputs from LDS ----
    if (tid < CC * 49) {
        const int cl  = tid / 49;
        const int pix = tid % 49;
        const int ph  = pix / 7;
        const int pw  = pix % 7;

        float acc = 0.0f;
        const float* patch = &s_patch[cl * PATCH_MAX];
#pragma unroll
        for (int iy = 0; iy < 2; ++iy) {
            const int sy = ph * 2 + iy;
            const int r0 = s_ylo[sy] * pw_cnt;
            const int r1 = s_yhi[sy] * pw_cnt;
            const float ly = s_ly[sy];
            const float hy = 1.0f - ly;
#pragma unroll
            for (int ix = 0; ix < 2; ++ix) {
                const int sx = pw * 2 + ix;
                const float lx = s_lx[sx];
                const float hx = 1.0f - lx;
                const float v00 = patch[r0 + s_xlo[sx]];
                const float v01 = patch[r0 + s_xhi[sx]];
                const float v10 = patch[r1 + s_xlo[sx]];
                const float v11 = patch[r1 + s_xhi[sx]];
                acc += hy * hx * v00 + hy * lx * v01 + ly * hx * v10 + ly * lx * v11;
            }
        }
        out[((size_t)k * NCH + c0) * 49 + tid] = acc * 0.25f;
    }
}

extern "C" void kernel_launch(void* const* d_in, const int* in_sizes, int n_in,
                              void* d_out, int out_size, void* d_ws, size_t ws_size,
                              hipStream_t stream)
{
    const float* f0 = (const float*)d_in[0];
    const float* f1 = (const float*)d_in[1];
    const float* f2 = (const float*)d_in[2];
    const float* f3 = (const float*)d_in[3];
    const float* boxes = (const float*)d_in[4];
    float* out = (float*)d_out;

    dim3 grid(NCH / CC, 512, 1);
    dim3 block(256, 1, 1);
    msroi_lds2_kernel<<<grid, block, 0, stream>>>(f0, f1, f2, f3, boxes, out);
}

// Round 5
// 176.911 us; speedup vs baseline: 1.4845x; 1.0168x over previous
//
#include <hip/hip_runtime.h>

// MultiScaleRoIAlign, round 5: setup-kernel + CC=8 LDS patch staging + read2-friendly phase 2.
// B=2, C=256, L=256 -> K=512 ROIs. out (K,256,7,7) fp32.
// Levels: (200,200,1/4) (100,100,1/8) (50,50,1/16) (25,25,1/32). SR=2, bilinear, avg 4.
//
// Kernel 1 (roi_setup): one thread per ROI -> d_ws params + tap tables
//   (element offsets, edge cases folded as l=0 so phase 2 reads pair [a],[a+1]).
// Kernel 2 (msroi_main): block = (8 channels, 1 ROI), 512 threads.
//   stage patch (padded odd row stride, zeroed pad col/row) -> 392 threads
//   compute 8x49 outputs; 12 LDS reads/output (4 tap-read2 + 8 value-read2).

#define OUT_HW 7
#define NCH 256
#define CC 8
#define PM 1152          // padded patch floats per channel (worst case ~1000)
#define WSTRIDE 80       // words per ROI in ws
#define NROI 512
#define THREADS 512

// ws per-ROI layout (words):
//  0 lvl, 1 px0, 2 py0, 3 pw_cnt, 4 pw_pad, 5 pdense, 6 W, 7 HW, 8 ph_cnt
//  16..29 xle[14] (xlo-px0; edge: last col, lx=0)
//  30..43 lx[14] (f32 bits)
//  44..57 r0e[14] ((ylo-py0)*pw_pad; edge: last row, ly=0)
//  58..71 ly[14] (f32 bits)

__device__ __forceinline__ void roi_scalars(const float* __restrict__ boxes, int k,
    int& lvl, int& H, int& W, float& x1, float& y1, float& bin_w, float& bin_h,
    int& px0, int& py0, int& pw_cnt, int& ph_cnt)
{
    float bx1 = boxes[k*4+0], by1 = boxes[k*4+1], bx2 = boxes[k*4+2], by2 = boxes[k*4+3];
    float area = (bx2-bx1)*(by2-by1);
    float s = sqrtf(area);
    float lvlf = floorf(4.0f + log2f(s*(1.0f/224.0f)) + 1e-6f);
    lvlf = fminf(fmaxf(lvlf, 2.0f), 5.0f);
    lvl = (int)lvlf - 2;
    float scale;
    if (lvl == 0)      { H=200; W=200; scale=0.25f;    }
    else if (lvl == 1) { H=100; W=100; scale=0.125f;   }
    else if (lvl == 2) { H=50;  W=50;  scale=0.0625f;  }
    else               { H=25;  W=25;  scale=0.03125f; }
    x1 = bx1*scale; y1 = by1*scale;
    float roi_w = fmaxf(bx2*scale - x1, 1.0f);
    float roi_h = fmaxf(by2*scale - y1, 1.0f);
    bin_w = roi_w*(1.0f/7.0f); bin_h = roi_h*(1.0f/7.0f);
    float c; int lo;
    c = fmaxf(x1 + 0.25f*bin_w, 0.0f); lo = (int)c; px0 = (lo >= W-1) ? (W-1) : lo;
    c = fmaxf(x1 + 6.75f*bin_w, 0.0f); lo = (int)c; int px1e = (lo >= W-1) ? (W-1) : (lo+1);
    c = fmaxf(y1 + 0.25f*bin_h, 0.0f); lo = (int)c; py0 = (lo >= H-1) ? (H-1) : lo;
    c = fmaxf(y1 + 6.75f*bin_h, 0.0f); lo = (int)c; int py1e = (lo >= H-1) ? (H-1) : (lo+1);
    pw_cnt = px1e - px0 + 1;
    ph_cnt = py1e - py0 + 1;
}

__global__ __launch_bounds__(64) void roi_setup(const float* __restrict__ boxes,
                                                int* __restrict__ ws)
{
    int k = blockIdx.x*64 + threadIdx.x;
    if (k >= NROI) return;
    int lvl, H, W, px0, py0, pw_cnt, ph_cnt;
    float x1, y1, bin_w, bin_h;
    roi_scalars(boxes, k, lvl, H, W, x1, y1, bin_w, bin_h, px0, py0, pw_cnt, ph_cnt);
    int pw_pad = (pw_cnt + 1) | 1;   // odd, >= pw_cnt+1 (room for +1 read + bank decorrelation)
    int* p = ws + k*WSTRIDE;
    p[0]=lvl; p[1]=px0; p[2]=py0; p[3]=pw_cnt; p[4]=pw_pad;
    p[5]=pw_cnt*ph_cnt; p[6]=W; p[7]=H*W; p[8]=ph_cnt;
    for (int i = 0; i < 14; ++i) {
        float c = fmaxf(x1 + ((float)i*0.5f + 0.25f)*bin_w, 0.0f);
        int lo = (int)c; int xle; float lx;
        if (lo >= W-1) { xle = (W-1) - px0; lx = 0.0f; }   // pair read hits zeroed pad col
        else           { xle = lo - px0;    lx = c - (float)lo; }
        p[16+i] = xle;
        p[30+i] = __float_as_int(lx);
    }
    for (int i = 0; i < 14; ++i) {
        float c = fmaxf(y1 + ((float)i*0.5f + 0.25f)*bin_h, 0.0f);
        int lo = (int)c; int r; float ly;
        if (lo >= H-1) { r = (H-1) - py0; ly = 0.0f; }     // +pw_pad read hits zeroed pad row
        else           { r = lo - py0;    ly = c - (float)lo; }
        p[44+i] = r*pw_pad;
        p[58+i] = __float_as_int(ly);
    }
}

template<bool USE_WS>
__global__ __launch_bounds__(THREADS) void msroi_main(
    const float* __restrict__ f0, const float* __restrict__ f1,
    const float* __restrict__ f2, const float* __restrict__ f3,
    const float* __restrict__ boxes, const int* __restrict__ ws,
    float* __restrict__ out)
{
    __shared__ float s_patch[CC*PM];
    __shared__ int   s_taps[56];   // [0..13] xle, [14..27] lx, [28..41] r0e, [42..55] ly

    const int tid = threadIdx.x;
    const int k  = blockIdx.y;
    const int c0 = blockIdx.x * CC;

    int lvl, px0, py0, pw_cnt, pw_pad, pdense, W, HW, ph_cnt;
    if constexpr (USE_WS) {
        const int* p = ws + k*WSTRIDE;   // uniform -> scalar loads
        lvl = p[0]; px0 = p[1]; py0 = p[2]; pw_cnt = p[3]; pw_pad = p[4];
        pdense = p[5]; W = p[6]; HW = p[7]; ph_cnt = p[8];
        if (tid < 56) s_taps[tid] = p[16 + tid];
    } else {
        int H; float x1, y1, bin_w, bin_h;
        roi_scalars(boxes, k, lvl, H, W, x1, y1, bin_w, bin_h, px0, py0, pw_cnt, ph_cnt);
        pw_pad = (pw_cnt + 1) | 1; pdense = pw_cnt*ph_cnt; HW = H*W;
        if (tid < 14) {
            float c = fmaxf(x1 + ((float)tid*0.5f + 0.25f)*bin_w, 0.0f);
            int lo = (int)c; int xle; float lx;
            if (lo >= W-1) { xle = (W-1) - px0; lx = 0.0f; }
            else           { xle = lo - px0;    lx = c - (float)lo; }
            s_taps[tid] = xle; s_taps[14+tid] = __float_as_int(lx);
        } else if (tid >= 64 && tid < 78) {
            int i = tid - 64;
            float c = fmaxf(y1 + ((float)i*0.5f + 0.25f)*bin_h, 0.0f);
            int lo = (int)c; int r; float ly;
            if (lo >= H-1) { r = (H-1) - py0; ly = 0.0f; }
            else           { r = lo - py0;    ly = c - (float)lo; }
            s_taps[28+i] = r*pw_pad; s_taps[42+i] = __float_as_int(ly);
        }
    }

    const float* feat = (lvl == 0) ? f0 : (lvl == 1) ? f1 : (lvl == 2) ? f2 : f3;
    const int b = k >> 8;
    const float* bp = feat + (size_t)(b*NCH + c0) * (size_t)HW;

    // zero pad slots: col pw_cnt for rows 0..ph_cnt, and pad row ph_cnt cols 0..pw_cnt-1
    int nz = ph_cnt + 1 + pw_cnt;
    for (int z = tid; z < nz; z += THREADS) {
        int wi = (z <= ph_cnt) ? (z*pw_pad + pw_cnt)
                               : (ph_cnt*pw_pad + (z - (ph_cnt + 1)));
#pragma unroll
        for (int j = 0; j < CC; ++j) s_patch[j*PM + wi] = 0.0f;
    }

    // stage: thread i -> dense patch pixel i, all 8 channels (coalesced rows)
    float inv_pw = 1.0f / (float)pw_cnt;
    for (int i = tid; i < pdense; i += THREADS) {
        int r = (int)((float)i * inv_pw);
        int col = i - r*pw_cnt;
        if (col < 0)             { col += pw_cnt; --r; }
        else if (col >= pw_cnt)  { col -= pw_cnt; ++r; }
        int go = (py0 + r)*W + (px0 + col);
        int wi = r*pw_pad + col;
#pragma unroll
        for (int j = 0; j < CC; ++j)
            s_patch[j*PM + wi] = bp[(size_t)j*(size_t)HW + (size_t)go];
    }
    __syncthreads();

    // phase 2: 392 threads, one output each; 12 LDS reads (read2-fusible pairs)
    if (tid < CC*49) {
        int cl = tid / 49, pix = tid - cl*49;
        int ph = pix / 7,  pw  = pix - ph*7;
        int cb = cl*PM;
        int xl0 = s_taps[2*pw]   + cb;
        int xl1 = s_taps[2*pw+1] + cb;
        float lx0 = __int_as_float(s_taps[14 + 2*pw]);
        float lx1 = __int_as_float(s_taps[15 + 2*pw]);
        int r00 = s_taps[28 + 2*ph];
        int r01 = s_taps[29 + 2*ph];
        float ly0 = __int_as_float(s_taps[42 + 2*ph]);
        float ly1 = __int_as_float(s_taps[43 + 2*ph]);
        float hx0 = 1.0f - lx0, hx1 = 1.0f - lx1;
        float hy0 = 1.0f - ly0, hy1 = 1.0f - ly1;

        float acc = 0.0f;
        {   // (iy=0, ix=0)
            int a = r00 + xl0, a2 = a + pw_pad;
            float v00 = s_patch[a], v01 = s_patch[a+1];
            float v10 = s_patch[a2], v11 = s_patch[a2+1];
            acc += hy0*(hx0*v00 + lx0*v01) + ly0*(hx0*v10 + lx0*v11);
        }
        {   // (iy=0, ix=1)
            int a = r00 + xl1, a2 = a + pw_pad;
            float v00 = s_patch[a], v01 = s_patch[a+1];
            float v10 = s_patch[a2], v11 = s_patch[a2+1];
            acc += hy0*(hx1*v00 + lx1*v01) + ly0*(hx1*v10 + lx1*v11);
        }
        {   // (iy=1, ix=0)
            int a = r01 + xl0, a2 = a + pw_pad;
            float v00 = s_patch[a], v01 = s_patch[a+1];
            float v10 = s_patch[a2], v11 = s_patch[a2+1];
            acc += hy1*(hx0*v00 + lx0*v01) + ly1*(hx0*v10 + lx0*v11);
        }
        {   // (iy=1, ix=1)
            int a = r01 + xl1, a2 = a + pw_pad;
            float v00 = s_patch[a], v01 = s_patch[a+1];
            float v10 = s_patch[a2], v11 = s_patch[a2+1];
            acc += hy1*(hx1*v00 + lx1*v01) + ly1*(hx1*v10 + lx1*v11);
        }
        out[((size_t)k*NCH + c0)*49 + tid] = acc * 0.25f;
    }
}

extern "C" void kernel_launch(void* const* d_in, const int* in_sizes, int n_in,
                              void* d_out, int out_size, void* d_ws, size_t ws_size,
                              hipStream_t stream)
{
    const float* f0 = (const float*)d_in[0];
    const float* f1 = (const float*)d_in[1];
    const float* f2 = (const float*)d_in[2];
    const float* f3 = (const float*)d_in[3];
    const float* boxes = (const float*)d_in[4];
    float* out = (float*)d_out;

    dim3 grid(NCH / CC, NROI, 1);
    dim3 block(THREADS, 1, 1);
    size_t need = (size_t)NROI * WSTRIDE * sizeof(int);

    if (d_ws != nullptr && ws_size >= need) {
        roi_setup<<<dim3((NROI + 63)/64), dim3(64), 0, stream>>>(boxes, (int*)d_ws);
        msroi_main<true><<<grid, block, 0, stream>>>(f0, f1, f2, f3, boxes,
                                                     (const int*)d_ws, out);
    } else {
        msroi_main<false><<<grid, block, 0, stream>>>(f0, f1, f2, f3, boxes,
                                                      nullptr, out);
    }
}